// Round 2
// baseline (712.567 us; speedup 1.0000x reference)
//
#include <hip/hip_runtime.h>
#include <hip/hip_bf16.h>
#include <math.h>

#define NB 16       // B
#define NL 32       // L
#define NH 768      // H
#define NE 200000   // E
#define NR 512      // R
#define NT 2000000  // T
#define FEPS 1e-6f

// ---------------------------------------------------------------------------
// K0: transpose heads (B,E) -> headsT (E,B).  Coalesced both sides via LDS.
// ---------------------------------------------------------------------------
__global__ __launch_bounds__(256) void k_transpose(const float* __restrict__ heads,
                                                   float* __restrict__ headsT) {
  __shared__ float tile[256][17];
  int e0 = blockIdx.x * 256;
  int tid = threadIdx.x;
  if (e0 + tid < NE) {
#pragma unroll
    for (int b = 0; b < NB; ++b)
      tile[tid][b] = heads[(size_t)b * NE + e0 + tid];
  }
  __syncthreads();
#pragma unroll
  for (int j = 0; j < 16; ++j) {
    int idx = j * 256 + tid;      // 0..4095 over (i,b)
    int i = idx >> 4, b = idx & 15;
    if (e0 + i < NE) headsT[(size_t)(e0 + i) * NB + b] = tile[i][b];
  }
}

// ---------------------------------------------------------------------------
// K1: Y(row,h) = act( X(row,:) @ W(:,h) + bias(h) ), rows = B*L, W is (H,H).
// 4 rows per block, 256 threads, thread owns h = {tid, tid+256, tid+512}.
// ACT: 0 = none, 1 = sigmoid.
// ---------------------------------------------------------------------------
template <int ACT>
__global__ __launch_bounds__(256) void k_rowmm(const float* __restrict__ X,
                                               const float* __restrict__ W,
                                               const float* __restrict__ bias,
                                               float* __restrict__ Y) {
  __shared__ float xs[4][NH];
  int row0 = blockIdx.x * 4;
  int tid = threadIdx.x;
  for (int r = 0; r < 4; ++r)
    for (int k = tid; k < NH; k += 256)
      xs[r][k] = X[(size_t)(row0 + r) * NH + k];
  __syncthreads();

  float acc[4][3] = {};
  for (int k = 0; k < NH; ++k) {
    float w0 = W[(size_t)k * NH + tid];
    float w1 = W[(size_t)k * NH + tid + 256];
    float w2 = W[(size_t)k * NH + tid + 512];
#pragma unroll
    for (int r = 0; r < 4; ++r) {
      float x = xs[r][k];
      acc[r][0] = fmaf(x, w0, acc[r][0]);
      acc[r][1] = fmaf(x, w1, acc[r][1]);
      acc[r][2] = fmaf(x, w2, acc[r][2]);
    }
  }
  float b0 = bias[tid], b1 = bias[tid + 256], b2 = bias[tid + 512];
#pragma unroll
  for (int r = 0; r < 4; ++r) {
    size_t base = (size_t)(row0 + r) * NH;
    float y0 = acc[r][0] + b0, y1 = acc[r][1] + b1, y2 = acc[r][2] + b2;
    if (ACT == 1) {
      y0 = 1.f / (1.f + expf(-y0));
      y1 = 1.f / (1.f + expf(-y1));
      y2 = 1.f / (1.f + expf(-y2));
    }
    Y[base + tid] = y0;
    Y[base + tid + 256] = y1;
    Y[base + tid + 512] = y2;
  }
}

// ---------------------------------------------------------------------------
// K2: per b: q_logits = qwh @ h_key^T (L,L); softmax(ax=2)*mask, renorm;
//     colsum over i; att = softmax(colsum)*mask, renorm.
// 1024 threads = (i,j) pairs; h_key staged in LDS tiles of 128 k (pad 129).
// ---------------------------------------------------------------------------
__global__ __launch_bounds__(1024) void k_attn(const float* __restrict__ qwh,
                                               const float* __restrict__ hkey,
                                               const float* __restrict__ mask,
                                               float* __restrict__ q_dist,
                                               float* __restrict__ att) {
  int b = blockIdx.x;
  int tid = threadIdx.x;
  int i = tid >> 5, j = tid & 31;
  __shared__ float hks[32 * 129];
  __shared__ float qd[32 * 33];

  const float* qrow = qwh + ((size_t)b * NL + i) * NH;
  float acc = 0.f;
  for (int k0 = 0; k0 < NH; k0 += 128) {
    __syncthreads();
    for (int idx = tid; idx < 32 * 128; idx += 1024) {
      int jj = idx >> 7, kk = idx & 127;
      hks[jj * 129 + kk] = hkey[((size_t)b * NL + jj) * NH + k0 + kk];
    }
    __syncthreads();
#pragma unroll 8
    for (int kk = 0; kk < 128; ++kk)
      acc = fmaf(qrow[k0 + kk], hks[j * 129 + kk], acc);
  }

  // softmax over j within each aligned 32-lane group
  float m = acc;
  for (int s = 16; s; s >>= 1) m = fmaxf(m, __shfl_xor(m, s, 32));
  float ex = expf(acc - m);
  float sum = ex;
  for (int s = 16; s; s >>= 1) sum += __shfl_xor(sum, s, 32);
  float p = ex / sum;
  p *= mask[b * NL + j];
  float s2 = p;
  for (int s = 16; s; s >>= 1) s2 += __shfl_xor(s2, s, 32);
  p = p / (s2 + FEPS);

  q_dist[((size_t)b * NL + i) * NL + j] = p;
  qd[i * 33 + j] = p;
  __syncthreads();

  if (tid < 32) {
    int jj = tid;
    float c = 0.f;
    for (int ii = 0; ii < 32; ++ii) c += qd[ii * 33 + jj];
    float mm = c;
    for (int s = 16; s; s >>= 1) mm = fmaxf(mm, __shfl_xor(mm, s, 32));
    float e2 = expf(c - mm);
    float ss = e2;
    for (int s = 16; s; s >>= 1) ss += __shfl_xor(ss, s, 32);
    float a = e2 / ss;
    a *= mask[b * NL + jj];
    float s3 = a;
    for (int s = 16; s; s >>= 1) s3 += __shfl_xor(s3, s, 32);
    a = a / (s3 + FEPS);
    att[b * NL + jj] = a;
  }
}

// ---------------------------------------------------------------------------
// K3: hop_ctx = q_dist @ q_hop; q_hop/prev_ctx update; ctx_h = att^T @ q_hop_new.
// One block per b, 256 threads; thread owns h = {tid, tid+256, tid+512};
// old q_hop columns held in registers (32x3 floats).
// ---------------------------------------------------------------------------
template <int STEP>
__global__ __launch_bounds__(256) void k_update(const float* __restrict__ qwh,
                                                const float* __restrict__ qhop_old,
                                                const float* __restrict__ q_dist,
                                                const float* __restrict__ att,
                                                const float* __restrict__ zbuf,
                                                const float* __restrict__ pc_old,
                                                float* __restrict__ qhop_new,
                                                float* __restrict__ pc_new,
                                                float* __restrict__ ctx_h) {
  int b = blockIdx.x;
  int tid = threadIdx.x;
  __shared__ float qd[NL * NL];
  __shared__ float as[NL];
  for (int idx = tid; idx < NL * NL; idx += 256) qd[idx] = q_dist[(size_t)b * NL * NL + idx];
  if (tid < NL) as[tid] = att[b * NL + tid];
  __syncthreads();

  float qh0[NL], qh1[NL], qh2[NL];
#pragma unroll
  for (int j = 0; j < NL; ++j) {
    const float* p = qhop_old + ((size_t)b * NL + j) * NH + tid;
    qh0[j] = p[0];
    qh1[j] = p[256];
    qh2[j] = p[512];
  }

  float c0 = 0.f, c1 = 0.f, c2 = 0.f;
  for (int l = 0; l < NL; ++l) {
    float h0 = 0.f, h1 = 0.f, h2 = 0.f;
#pragma unroll
    for (int j = 0; j < NL; ++j) {
      float d = qd[l * NL + j];
      h0 = fmaf(d, qh0[j], h0);
      h1 = fmaf(d, qh1[j], h1);
      h2 = fmaf(d, qh2[j], h2);
    }
    size_t base = ((size_t)b * NL + l) * NH + tid;
    float qn0, qn1, qn2;
    if (STEP == 0) {
      qn0 = qwh[base] + h0;
      qn1 = qwh[base + 256] + h1;
      qn2 = qwh[base + 512] + h2;
      qhop_new[base] = qn0;
      qhop_new[base + 256] = qn1;
      qhop_new[base + 512] = qn2;
      pc_new[base] = h0;
      pc_new[base + 256] = h1;
      pc_new[base + 512] = h2;
    } else {
      float t0 = zbuf[base] * pc_old[base];
      float t1 = zbuf[base + 256] * pc_old[base + 256];
      float t2 = zbuf[base + 512] * pc_old[base + 512];
      qn0 = qwh[base] + h0 + t0;
      qn1 = qwh[base + 256] + h1 + t1;
      qn2 = qwh[base + 512] + h2 + t2;
    }
    float a = as[l];
    c0 = fmaf(a, qn0, c0);
    c1 = fmaf(a, qn1, c1);
    c2 = fmaf(a, qn2, c2);
  }
  size_t cb = ((size_t)b * 2 + STEP) * NH + tid;
  ctx_h[cb] = c0;
  ctx_h[cb + 256] = c1;
  ctx_h[cb + 512] = c2;
}

// ---------------------------------------------------------------------------
// K4: rel_dist^T (R,B): relT[r*16+b] = sigmoid(ctx_h[b,step,:] . rel_w[:,r] + rel_b[r])
// grid = B*2 blocks (b, r-half), 256 threads = r within half.
// ---------------------------------------------------------------------------
__global__ __launch_bounds__(256) void k_rel(const float* __restrict__ ctx_h, int step,
                                             const float* __restrict__ rel_w,
                                             const float* __restrict__ rel_b,
                                             float* __restrict__ relT) {
  int b = blockIdx.x >> 1;
  int r = ((blockIdx.x & 1) << 8) + threadIdx.x;
  const float* c = ctx_h + ((size_t)b * 2 + step) * NH;
  float acc = rel_b[r];
  for (int h = 0; h < NH; ++h) acc = fmaf(c[h], rel_w[(size_t)h * NR + r], acc);
  relT[r * NB + b] = 1.f / (1.f + expf(-acc));
}

// ---------------------------------------------------------------------------
// K5: follow. dstT[obj*16+b] += src(subj,b) * relT[rel*16+b].
// One (edge,b) unit per lane-iteration; 16-lane groups share index loads and
// touch one 64B line each for gather / relT / scatter.  Grid-stride x4 with
// full unroll -> 4 independent memory chains per thread (MLP), 31250 blocks.
// Index streams are single-use -> nontemporal to protect L2/L3 residency of
// srcT / relT / dstT.  CLAMP fuses the previous step's z_norm: min(x,1).
// ---------------------------------------------------------------------------
template <int CLAMP>
__global__ __launch_bounds__(256) void k_follow(const int* __restrict__ subj,
                                                const int* __restrict__ rel,
                                                const int* __restrict__ obj,
                                                const float* __restrict__ srcT,
                                                const float* __restrict__ relT,
                                                float* __restrict__ dstT) {
  const size_t stride = (size_t)gridDim.x * 256;
  size_t gid = (size_t)blockIdx.x * 256 + threadIdx.x;
#pragma unroll 4
  for (int it = 0; it < 4; ++it, gid += stride) {
    int k = (int)(gid >> 4);
    int b = (int)(gid & 15);
    int s = __builtin_nontemporal_load(&subj[k]);
    int r = __builtin_nontemporal_load(&rel[k]);
    int o = __builtin_nontemporal_load(&obj[k]);
    float x = srcT[(size_t)s * NB + b];
    if (CLAMP) x = fminf(x, 1.f);
    x *= relT[r * NB + b];
    atomicAdd(&dstT[(size_t)o * NB + b], x);
  }
}

// ---------------------------------------------------------------------------
// K6: hop attention over the 2 steps: softmax_t( ctx_h[b,t,:] . hop_w + hop_b )
// ---------------------------------------------------------------------------
__global__ __launch_bounds__(256) void k_hopattn(const float* __restrict__ ctx_h,
                                                 const float* __restrict__ hop_w,
                                                 const float* __restrict__ hop_b,
                                                 float* __restrict__ hop_attn) {
  int tid = threadIdx.x;
  int pair = tid >> 3;  // 0..31 = (b,t)
  int sub = tid & 7;
  int b = pair >> 1, t = pair & 1;
  float acc = 0.f;
  for (int h = sub; h < NH; h += 8)
    acc = fmaf(ctx_h[((size_t)b * 2 + t) * NH + h], hop_w[h], acc);
  for (int s = 4; s; s >>= 1) acc += __shfl_xor(acc, s, 8);
  __shared__ float lg[32];
  if (sub == 0) lg[pair] = acc + hop_b[0];
  __syncthreads();
  if (tid < 16) {
    float l0 = lg[tid * 2], l1 = lg[tid * 2 + 1];
    float m = fmaxf(l0, l1);
    float e0 = expf(l0 - m), e1 = expf(l1 - m);
    float s = e0 + e1;
    hop_attn[tid * 2] = e0 / s;
    hop_attn[tid * 2 + 1] = e1 / s;
  }
}

// ---------------------------------------------------------------------------
// K7: e_score[b][e] = a0[b]*min(e0T[e][b],1) + a1[b]*min(e1T[e][b],1)
// LDS-tiled so reads (E,B-major) and writes (B,E-major) are both coalesced.
// ---------------------------------------------------------------------------
__global__ __launch_bounds__(256) void k_combine(const float* __restrict__ e0T,
                                                 const float* __restrict__ e1T,
                                                 const float* __restrict__ hop_attn,
                                                 float* __restrict__ out) {
  __shared__ float s0[256 * 17], s1[256 * 17];
  int e0 = blockIdx.x * 256;
  int tid = threadIdx.x;
#pragma unroll
  for (int j = 0; j < 16; ++j) {
    int idx = j * 256 + tid;  // (i,b)
    int i = idx >> 4, b = idx & 15;
    if (e0 + i < NE) {
      s0[i * 17 + b] = fminf(e0T[(size_t)e0 * NB + idx], 1.f);
      s1[i * 17 + b] = fminf(e1T[(size_t)e0 * NB + idx], 1.f);
    }
  }
  __syncthreads();
  if (e0 + tid < NE) {
#pragma unroll
    for (int b = 0; b < NB; ++b) {
      float a0 = hop_attn[b * 2], a1 = hop_attn[b * 2 + 1];
      out[(size_t)b * NE + e0 + tid] = a0 * s0[tid * 17 + b] + a1 * s1[tid * 17 + b];
    }
  }
}

// ---------------------------------------------------------------------------
extern "C" void kernel_launch(void* const* d_in, const int* in_sizes, int n_in,
                              void* d_out, int out_size, void* d_ws, size_t ws_size,
                              hipStream_t stream) {
  const float* heads = (const float*)d_in[0];
  const float* q_word_h = (const float*)d_in[1];
  const float* mask = (const float*)d_in[2];
  const int* subj = (const int*)d_in[3];
  const int* rel = (const int*)d_in[4];
  const int* obj = (const int*)d_in[5];
  const float* key_w = (const float*)d_in[6];
  const float* key_b = (const float*)d_in[7];
  const float* rel_w = (const float*)d_in[8];
  const float* rel_b = (const float*)d_in[9];
  const float* hop_w = (const float*)d_in[10];
  const float* hop_b = (const float*)d_in[11];
  const float* hw_w = (const float*)d_in[12];
  const float* hw_b = (const float*)d_in[13];

  float* ws = (float*)d_ws;
  size_t o = 0;
  float* headsT = ws + o; o += (size_t)NE * NB;
  float* e0T    = ws + o; o += (size_t)NE * NB;
  float* e1T    = ws + o; o += (size_t)NE * NB;
  float* h_key  = ws + o; o += (size_t)NB * NL * NH;
  float* qhopB  = ws + o; o += (size_t)NB * NL * NH;
  float* pcB    = ws + o; o += (size_t)NB * NL * NH;
  float* zbuf   = ws + o; o += (size_t)NB * NL * NH;
  float* q_dist = ws + o; o += (size_t)NB * NL * NL;
  float* att    = ws + o; o += (size_t)NB * NL;
  float* ctx_h  = ws + o; o += (size_t)NB * 2 * NH;
  float* relT   = ws + o; o += (size_t)NR * NB;
  float* hop_attn = ws + o; o += (size_t)NB * 2;

  const int EB_BLOCKS = (NE + 255) / 256;              // 782
  const int FOLLOW_BLOCKS = (NT * 16) / (256 * 4);     // 31250 (exact)

  hipMemsetAsync(e0T, 0, (size_t)NE * NB * sizeof(float), stream);
  hipMemsetAsync(e1T, 0, (size_t)NE * NB * sizeof(float), stream);
  k_transpose<<<EB_BLOCKS, 256, 0, stream>>>(heads, headsT);

  // ---- step 0 (q_hop == q_word_h) ----
  k_rowmm<0><<<(NB * NL) / 4, 256, 0, stream>>>(q_word_h, key_w, key_b, h_key);
  k_attn<<<NB, 1024, 0, stream>>>(q_word_h, h_key, mask, q_dist, att);
  k_update<0><<<NB, 256, 0, stream>>>(q_word_h, q_word_h, q_dist, att, nullptr, nullptr,
                                      qhopB, pcB, ctx_h);
  k_rel<<<NB * 2, 256, 0, stream>>>(ctx_h, 0, rel_w, rel_b, relT);
  k_follow<0><<<FOLLOW_BLOCKS, 256, 0, stream>>>(subj, rel, obj, headsT, relT, e0T);

  // ---- step 1 ----
  k_rowmm<0><<<(NB * NL) / 4, 256, 0, stream>>>(qhopB, key_w, key_b, h_key);
  k_attn<<<NB, 1024, 0, stream>>>(q_word_h, h_key, mask, q_dist, att);
  k_rowmm<1><<<(NB * NL) / 4, 256, 0, stream>>>(pcB, hw_w, hw_b, zbuf);
  k_update<1><<<NB, 256, 0, stream>>>(q_word_h, qhopB, q_dist, att, zbuf, pcB,
                                      nullptr, nullptr, ctx_h);
  k_rel<<<NB * 2, 256, 0, stream>>>(ctx_h, 1, rel_w, rel_b, relT);
  k_follow<1><<<FOLLOW_BLOCKS, 256, 0, stream>>>(subj, rel, obj, e0T, relT, e1T);

  // ---- epilogue ----
  k_hopattn<<<1, 256, 0, stream>>>(ctx_h, hop_w, hop_b, hop_attn);
  k_combine<<<EB_BLOCKS, 256, 0, stream>>>(e0T, e1T, hop_attn, (float*)d_out);
}

// Round 6
// 592.332 us; speedup vs baseline: 1.2030x; 1.2030x over previous
//
#include <hip/hip_runtime.h>
#include <hip/hip_bf16.h>
#include <math.h>

#define NB 16       // B
#define NL 32       // L
#define NH 768      // H
#define NE 200000   // E
#define NR 512      // R
#define NT 2000000  // T
#define FEPS 1e-6f

typedef float f32x4 __attribute__((ext_vector_type(4)));

// ---------------------------------------------------------------------------
// K0: transpose heads (B,E) -> headsT (E,B).  Coalesced both sides via LDS.
// ---------------------------------------------------------------------------
__global__ __launch_bounds__(256) void k_transpose(const float* __restrict__ heads,
                                                   float* __restrict__ headsT) {
  __shared__ float tile[256][17];
  int e0 = blockIdx.x * 256;
  int tid = threadIdx.x;
  if (e0 + tid < NE) {
#pragma unroll
    for (int b = 0; b < NB; ++b)
      tile[tid][b] = heads[(size_t)b * NE + e0 + tid];
  }
  __syncthreads();
#pragma unroll
  for (int j = 0; j < 16; ++j) {
    int idx = j * 256 + tid;      // 0..4095 over (i,b)
    int i = idx >> 4, b = idx & 15;
    if (e0 + i < NE) headsT[(size_t)(e0 + i) * NB + b] = tile[i][b];
  }
}

// ---------------------------------------------------------------------------
// K1: dual row-MM.  Blocks < nblk0 compute Y0 = act0(X0 @ W0 + b0) rows;
// blocks >= nblk0 compute Y1 = act1(X1 @ W1 + b1).  2 rows per block,
// 256 threads, thread owns h = {tid, tid+256, tid+512}.  act: 0=none,1=sigmoid.
// (Single launch covers both step-1 projections; step 0 passes nblk0=grid.)
// ---------------------------------------------------------------------------
__global__ __launch_bounds__(256) void k_rowmm2(const float* __restrict__ X0,
                                                const float* __restrict__ W0,
                                                const float* __restrict__ b0,
                                                float* __restrict__ Y0, int act0,
                                                const float* __restrict__ X1,
                                                const float* __restrict__ W1,
                                                const float* __restrict__ b1,
                                                float* __restrict__ Y1, int act1,
                                                int nblk0) {
  const float* X; const float* W; const float* bias; float* Y; int act, row0;
  int blk = blockIdx.x;
  if (blk < nblk0) { X = X0; W = W0; bias = b0; Y = Y0; act = act0; row0 = blk * 2; }
  else            { X = X1; W = W1; bias = b1; Y = Y1; act = act1; row0 = (blk - nblk0) * 2; }

  __shared__ float xs[2][NH];
  int tid = threadIdx.x;
  for (int r = 0; r < 2; ++r)
    for (int k = tid; k < NH; k += 256)
      xs[r][k] = X[(size_t)(row0 + r) * NH + k];
  __syncthreads();

  float acc[2][3] = {};
  for (int k = 0; k < NH; ++k) {
    float w0 = W[(size_t)k * NH + tid];
    float w1 = W[(size_t)k * NH + tid + 256];
    float w2 = W[(size_t)k * NH + tid + 512];
#pragma unroll
    for (int r = 0; r < 2; ++r) {
      float x = xs[r][k];
      acc[r][0] = fmaf(x, w0, acc[r][0]);
      acc[r][1] = fmaf(x, w1, acc[r][1]);
      acc[r][2] = fmaf(x, w2, acc[r][2]);
    }
  }
  float bb0 = bias[tid], bb1 = bias[tid + 256], bb2 = bias[tid + 512];
#pragma unroll
  for (int r = 0; r < 2; ++r) {
    size_t base = (size_t)(row0 + r) * NH;
    float y0 = acc[r][0] + bb0, y1 = acc[r][1] + bb1, y2 = acc[r][2] + bb2;
    if (act == 1) {
      y0 = 1.f / (1.f + expf(-y0));
      y1 = 1.f / (1.f + expf(-y1));
      y2 = 1.f / (1.f + expf(-y2));
    }
    Y[base + tid] = y0;
    Y[base + tid + 256] = y1;
    Y[base + tid + 512] = y2;
  }
}

// ---------------------------------------------------------------------------
// K2: per b: q_logits = qwh @ h_key^T (L,L); softmax(ax=2)*mask, renorm;
//     colsum over i; att = softmax(colsum)*mask, renorm.
// 1024 threads = (i,j) pairs; q rows and h_key rows staged in LDS via float4
// global loads (1024 thr = 32 rows x 32 f4 x 2 arrays, 16B-aligned);
// LDS rows stride 129 (=1 mod 32 banks) -> conflict-free inner loop.
// ---------------------------------------------------------------------------
__global__ __launch_bounds__(1024) void k_attn(const float* __restrict__ qwh,
                                               const float* __restrict__ hkey,
                                               const float* __restrict__ mask,
                                               float* __restrict__ q_dist,
                                               float* __restrict__ att) {
  int b = blockIdx.x;
  int tid = threadIdx.x;
  int i = tid >> 5, j = tid & 31;
  __shared__ float hks[32 * 129];
  __shared__ float qs[32 * 129];
  __shared__ float qd[32 * 33];

  float acc = 0.f;
  for (int k0 = 0; k0 < NH; k0 += 128) {
    __syncthreads();
    {
      int jj = tid >> 5;      // row 0..31
      int kk4 = tid & 31;     // float4 index 0..31
      size_t goff = ((size_t)b * NL + jj) * NH + k0 + kk4 * 4;
      f32x4 hv = *(const f32x4*)(hkey + goff);
      f32x4 qv = *(const f32x4*)(qwh + goff);
      int base = jj * 129 + kk4 * 4;
      hks[base] = hv.x; hks[base + 1] = hv.y; hks[base + 2] = hv.z; hks[base + 3] = hv.w;
      qs[base] = qv.x;  qs[base + 1] = qv.y;  qs[base + 2] = qv.z;  qs[base + 3] = qv.w;
    }
    __syncthreads();
#pragma unroll 8
    for (int kk = 0; kk < 128; ++kk)
      acc = fmaf(qs[i * 129 + kk], hks[j * 129 + kk], acc);
  }

  // softmax over j within each aligned 32-lane group
  float m = acc;
  for (int s = 16; s; s >>= 1) m = fmaxf(m, __shfl_xor(m, s, 32));
  float ex = expf(acc - m);
  float sum = ex;
  for (int s = 16; s; s >>= 1) sum += __shfl_xor(sum, s, 32);
  float p = ex / sum;
  p *= mask[b * NL + j];
  float s2 = p;
  for (int s = 16; s; s >>= 1) s2 += __shfl_xor(s2, s, 32);
  p = p / (s2 + FEPS);

  q_dist[((size_t)b * NL + i) * NL + j] = p;
  qd[i * 33 + j] = p;
  __syncthreads();

  if (tid < 32) {
    int jj = tid;
    float c = 0.f;
    for (int ii = 0; ii < 32; ++ii) c += qd[ii * 33 + jj];
    float mm = c;
    for (int s = 16; s; s >>= 1) mm = fmaxf(mm, __shfl_xor(mm, s, 32));
    float e2 = expf(c - mm);
    float ss = e2;
    for (int s = 16; s; s >>= 1) ss += __shfl_xor(ss, s, 32);
    float a = e2 / ss;
    a *= mask[b * NL + jj];
    float s3 = a;
    for (int s = 16; s; s >>= 1) s3 += __shfl_xor(s3, s, 32);
    a = a / (s3 + FEPS);
    att[b * NL + jj] = a;
  }
}

// ---------------------------------------------------------------------------
// K3: fused per-b update + rel projection.
// hop_ctx = q_dist @ q_hop; q_hop/prev_ctx update; ctx_h = att^T @ q_hop_new;
// then relT[r*16+b] = sigmoid(ctx_h . rel_w[:,r] + rel_b[r]) for all r.
// One block per b, 256 threads; thread owns h = {tid, tid+256, tid+512}.
// ---------------------------------------------------------------------------
template <int STEP>
__global__ __launch_bounds__(256) void k_update_rel(const float* __restrict__ qwh,
                                                    const float* __restrict__ qhop_old,
                                                    const float* __restrict__ q_dist,
                                                    const float* __restrict__ att,
                                                    const float* __restrict__ zbuf,
                                                    const float* __restrict__ pc_old,
                                                    float* __restrict__ qhop_new,
                                                    float* __restrict__ pc_new,
                                                    float* __restrict__ ctx_h,
                                                    const float* __restrict__ rel_w,
                                                    const float* __restrict__ rel_b,
                                                    float* __restrict__ relT) {
  int b = blockIdx.x;
  int tid = threadIdx.x;
  __shared__ float qd[NL * NL];
  __shared__ float as[NL];
  __shared__ float ctx_s[NH];
  for (int idx = tid; idx < NL * NL; idx += 256) qd[idx] = q_dist[(size_t)b * NL * NL + idx];
  if (tid < NL) as[tid] = att[b * NL + tid];
  __syncthreads();

  float qh0[NL], qh1[NL], qh2[NL];
#pragma unroll
  for (int j = 0; j < NL; ++j) {
    const float* p = qhop_old + ((size_t)b * NL + j) * NH + tid;
    qh0[j] = p[0];
    qh1[j] = p[256];
    qh2[j] = p[512];
  }

  float c0 = 0.f, c1 = 0.f, c2 = 0.f;
  for (int l = 0; l < NL; ++l) {
    float h0 = 0.f, h1 = 0.f, h2 = 0.f;
#pragma unroll
    for (int j = 0; j < NL; ++j) {
      float d = qd[l * NL + j];
      h0 = fmaf(d, qh0[j], h0);
      h1 = fmaf(d, qh1[j], h1);
      h2 = fmaf(d, qh2[j], h2);
    }
    size_t base = ((size_t)b * NL + l) * NH + tid;
    float qn0, qn1, qn2;
    if (STEP == 0) {
      qn0 = qwh[base] + h0;
      qn1 = qwh[base + 256] + h1;
      qn2 = qwh[base + 512] + h2;
      qhop_new[base] = qn0;
      qhop_new[base + 256] = qn1;
      qhop_new[base + 512] = qn2;
      pc_new[base] = h0;
      pc_new[base + 256] = h1;
      pc_new[base + 512] = h2;
    } else {
      float t0 = zbuf[base] * pc_old[base];
      float t1 = zbuf[base + 256] * pc_old[base + 256];
      float t2 = zbuf[base + 512] * pc_old[base + 512];
      qn0 = qwh[base] + h0 + t0;
      qn1 = qwh[base + 256] + h1 + t1;
      qn2 = qwh[base + 512] + h2 + t2;
    }
    float a = as[l];
    c0 = fmaf(a, qn0, c0);
    c1 = fmaf(a, qn1, c1);
    c2 = fmaf(a, qn2, c2);
  }
  size_t cb = ((size_t)b * 2 + STEP) * NH + tid;
  ctx_h[cb] = c0;
  ctx_h[cb + 256] = c1;
  ctx_h[cb + 512] = c2;
  ctx_s[tid] = c0;
  ctx_s[tid + 256] = c1;
  ctx_s[tid + 512] = c2;
  __syncthreads();

  // rel projection: this thread owns r = tid and tid+256
  float accA = rel_b[tid], accB = rel_b[tid + 256];
  for (int h = 0; h < NH; ++h) {
    float c = ctx_s[h];  // LDS broadcast
    accA = fmaf(c, rel_w[(size_t)h * NR + tid], accA);
    accB = fmaf(c, rel_w[(size_t)h * NR + tid + 256], accB);
  }
  relT[tid * NB + b] = 1.f / (1.f + expf(-accA));
  relT[(tid + 256) * NB + b] = 1.f / (1.f + expf(-accB));
}

// ---------------------------------------------------------------------------
// K5: follow (verified round-1 form, 112us). One (edge,b) per lane-iteration;
// 16-lane groups share index loads and touch one 64B line each for
// gather / relT / scatter.  Grid-stride x4 unrolled -> 4 independent memory
// chains per thread.  Index streams single-use -> nontemporal.
// CLAMP fuses prev-step z_norm: min(x,1).
// ---------------------------------------------------------------------------
template <int CLAMP>
__global__ __launch_bounds__(256) void k_follow(const int* __restrict__ subj,
                                                const int* __restrict__ rel,
                                                const int* __restrict__ obj,
                                                const float* __restrict__ srcT,
                                                const float* __restrict__ relT,
                                                float* __restrict__ dstT) {
  const size_t stride = (size_t)gridDim.x * 256;
  size_t gid = (size_t)blockIdx.x * 256 + threadIdx.x;
#pragma unroll 4
  for (int it = 0; it < 4; ++it, gid += stride) {
    int k = (int)(gid >> 4);
    int b = (int)(gid & 15);
    int s = __builtin_nontemporal_load(&subj[k]);
    int r = __builtin_nontemporal_load(&rel[k]);
    int o = __builtin_nontemporal_load(&obj[k]);
    float x = srcT[(size_t)s * NB + b];
    if (CLAMP) x = fminf(x, 1.f);
    x *= relT[r * NB + b];
    atomicAdd(&dstT[(size_t)o * NB + b], x);
  }
}

// ---------------------------------------------------------------------------
// K7: hop-attn (inlined, redundant per block) + combine:
// e_score[b][e] = a0[b]*min(e0T[e][b],1) + a1[b]*min(e1T[e][b],1)
// LDS-tiled so reads (E,B-major) and writes (B,E-major) are both coalesced.
// ---------------------------------------------------------------------------
__global__ __launch_bounds__(256) void k_combine(const float* __restrict__ e0T,
                                                 const float* __restrict__ e1T,
                                                 const float* __restrict__ ctx_h,
                                                 const float* __restrict__ hop_w,
                                                 const float* __restrict__ hop_b,
                                                 float* __restrict__ out) {
  __shared__ float s0[256 * 17], s1[256 * 17];
  __shared__ float lg[32];
  __shared__ float ha[32];
  int tid = threadIdx.x;

  // hop attention: 32 (b,t) pairs x 8 lanes each
  {
    int pair = tid >> 3, sub = tid & 7;
    int bb = pair >> 1, t = pair & 1;
    float acc = 0.f;
    for (int h = sub; h < NH; h += 8)
      acc = fmaf(ctx_h[((size_t)bb * 2 + t) * NH + h], hop_w[h], acc);
    for (int s = 4; s; s >>= 1) acc += __shfl_xor(acc, s, 8);
    if (sub == 0) lg[pair] = acc + hop_b[0];
  }
  __syncthreads();
  if (tid < 16) {
    float l0 = lg[tid * 2], l1 = lg[tid * 2 + 1];
    float m = fmaxf(l0, l1);
    float e0 = expf(l0 - m), e1 = expf(l1 - m);
    float s = e0 + e1;
    ha[tid * 2] = e0 / s;
    ha[tid * 2 + 1] = e1 / s;
  }
  __syncthreads();

  int e0 = blockIdx.x * 256;
#pragma unroll
  for (int j = 0; j < 16; ++j) {
    int idx = j * 256 + tid;  // (i,b)
    int i = idx >> 4, b = idx & 15;
    if (e0 + i < NE) {
      s0[i * 17 + b] = fminf(e0T[(size_t)e0 * NB + idx], 1.f);
      s1[i * 17 + b] = fminf(e1T[(size_t)e0 * NB + idx], 1.f);
    }
  }
  __syncthreads();
  if (e0 + tid < NE) {
#pragma unroll
    for (int b = 0; b < NB; ++b) {
      float a0 = ha[b * 2], a1 = ha[b * 2 + 1];
      out[(size_t)b * NE + e0 + tid] = a0 * s0[tid * 17 + b] + a1 * s1[tid * 17 + b];
    }
  }
}

// ---------------------------------------------------------------------------
extern "C" void kernel_launch(void* const* d_in, const int* in_sizes, int n_in,
                              void* d_out, int out_size, void* d_ws, size_t ws_size,
                              hipStream_t stream) {
  const float* heads = (const float*)d_in[0];
  const float* q_word_h = (const float*)d_in[1];
  const float* mask = (const float*)d_in[2];
  const int* subj = (const int*)d_in[3];
  const int* rel = (const int*)d_in[4];
  const int* obj = (const int*)d_in[5];
  const float* key_w = (const float*)d_in[6];
  const float* key_b = (const float*)d_in[7];
  const float* rel_w = (const float*)d_in[8];
  const float* rel_b = (const float*)d_in[9];
  const float* hop_w = (const float*)d_in[10];
  const float* hop_b = (const float*)d_in[11];
  const float* hw_w = (const float*)d_in[12];
  const float* hw_b = (const float*)d_in[13];

  float* ws = (float*)d_ws;
  size_t o = 0;
  float* headsT = ws + o; o += (size_t)NE * NB;
  float* e0T    = ws + o; o += (size_t)NE * NB;   // contiguous with e1T:
  float* e1T    = ws + o; o += (size_t)NE * NB;   // single memset covers both
  float* h_key  = ws + o; o += (size_t)NB * NL * NH;
  float* qhopB  = ws + o; o += (size_t)NB * NL * NH;
  float* pcB    = ws + o; o += (size_t)NB * NL * NH;
  float* zbuf   = ws + o; o += (size_t)NB * NL * NH;
  float* q_dist = ws + o; o += (size_t)NB * NL * NL;
  float* att    = ws + o; o += (size_t)NB * NL;
  float* ctx_h  = ws + o; o += (size_t)NB * 2 * NH;
  float* relT   = ws + o; o += (size_t)NR * NB;

  const int EB_BLOCKS = (NE + 255) / 256;              // 782
  const int FOLLOW_BLOCKS = (NT * 16) / (256 * 4);     // 31250 (exact)
  const int MM_BLOCKS = (NB * NL) / 2;                 // 256 (2 rows/block)

  hipMemsetAsync(e0T, 0, (size_t)2 * NE * NB * sizeof(float), stream);
  k_transpose<<<EB_BLOCKS, 256, 0, stream>>>(heads, headsT);

  // ---- step 0 (q_hop == q_word_h) ----
  k_rowmm2<<<MM_BLOCKS, 256, 0, stream>>>(q_word_h, key_w, key_b, h_key, 0,
                                          q_word_h, key_w, key_b, h_key, 0, MM_BLOCKS);
  k_attn<<<NB, 1024, 0, stream>>>(q_word_h, h_key, mask, q_dist, att);
  k_update_rel<0><<<NB, 256, 0, stream>>>(q_word_h, q_word_h, q_dist, att, nullptr,
                                          nullptr, qhopB, pcB, ctx_h, rel_w, rel_b, relT);
  k_follow<0><<<FOLLOW_BLOCKS, 256, 0, stream>>>(subj, rel, obj, headsT, relT, e0T);

  // ---- step 1 (key-proj of qhopB and hw-proj of pcB fused in one launch) ----
  k_rowmm2<<<2 * MM_BLOCKS, 256, 0, stream>>>(qhopB, key_w, key_b, h_key, 0,
                                              pcB, hw_w, hw_b, zbuf, 1, MM_BLOCKS);
  k_attn<<<NB, 1024, 0, stream>>>(q_word_h, h_key, mask, q_dist, att);
  k_update_rel<1><<<NB, 256, 0, stream>>>(q_word_h, qhopB, q_dist, att, zbuf, pcB,
                                          nullptr, nullptr, ctx_h, rel_w, rel_b, relT);
  k_follow<1><<<FOLLOW_BLOCKS, 256, 0, stream>>>(subj, rel, obj, e0T, relT, e1T);

  // ---- epilogue (hop-attn fused into combine) ----
  k_combine<<<EB_BLOCKS, 256, 0, stream>>>(e0T, e1T, ctx_h, hop_w, hop_b, (float*)d_out);
}